// Round 6
// baseline (278.736 us; speedup 1.0000x reference)
//
#include <hip/hip_runtime.h>
#include <hip/hip_bf16.h>
#include <cstdint>
#include <cstddef>

// B=4, S=4096, D=1024, E=10, R=4, TOPK=2, SCALING=0.25
#define D_DIM 1024
#define E_NUM 10

typedef __attribute__((ext_vector_type(8))) short bf16x8;
typedef __attribute__((ext_vector_type(4))) float f32x4;
typedef unsigned short u16;
typedef unsigned int u32;

__device__ __forceinline__ u16 f2bf(float f) {
  union { float f; u32 u; } v; v.f = f;
  u32 r = v.u + 0x7fffu + ((v.u >> 16) & 1u);   // RNE
  return (u16)(r >> 16);
}
__device__ __forceinline__ float bf2f(u16 u) {
  union { u32 u; float f; } v; v.u = ((u32)u) << 16; return v.f;
}
__device__ __forceinline__ float dot4(float4 a, float4 b) {
  return a.x * b.x + a.y * b.y + a.z * b.z + a.w * b.w;
}

// ---------------- W_base fp32 -> bf16 (R2-proven) ----------------
__global__ void conv_w(const float* __restrict__ W, u16* __restrict__ Wb) {
  const int i = (blockIdx.x * 256 + threadIdx.x) * 8;
  float4 a = *(const float4*)(W + i);
  float4 b = *(const float4*)(W + i + 4);
  *(ushort4*)(Wb + i)     = make_ushort4(f2bf(a.x), f2bf(a.y), f2bf(a.z), f2bf(a.w));
  *(ushort4*)(Wb + i + 4) = make_ushort4(f2bf(b.x), f2bf(b.y), f2bf(b.z), f2bf(b.w));
}

// ---------------- gating + LoRA-down prep: R2 math, ILP-restructured --------
// 256 blocks x 1024 thr (16 waves); wave w owns 4 tokens held in regs at once.
// Exact R2 arithmetic per token: fp32 logits via LDS gW + butterfly reduce,
// h via bf16 LDS lora_down; top-2 tie-break identical.
__global__ __launch_bounds__(1024)
void moe_prep2(const float* __restrict__ x, const float* __restrict__ gW,
               const float* __restrict__ gb, const float* __restrict__ ld,
               int* __restrict__ ids, float* __restrict__ cvals) {
  __shared__ float sgW[E_NUM * D_DIM];            // 40 KB
  __shared__ u16   sld[E_NUM * 4 * D_DIM];        // 80 KB
  __shared__ float sgb[16];
  const int tid = threadIdx.x;
  for (int i = tid; i < E_NUM * D_DIM; i += 1024) sgW[i] = gW[i];
  for (int i = tid; i < E_NUM * 4 * D_DIM; i += 1024) sld[i] = f2bf(ld[i]);
  if (tid < E_NUM) sgb[tid] = gb[tid];
  __syncthreads();

  const int lane = tid & 63, w = tid >> 6;
  const int tbase = blockIdx.x * 64 + w * 4;

  // 4 tokens' x slices in regs (64 VGPR)
  float4 xv[4][4];
#pragma unroll
  for (int tok = 0; tok < 4; ++tok)
#pragma unroll
    for (int j = 0; j < 4; ++j)
      xv[tok][j] = *(const float4*)(x + (size_t)(tbase + tok) * D_DIM + j * 256 + lane * 4);

  // ---- logits: W-chunk shared across 4 tokens; batched butterflies ----
  float lg[4][E_NUM];
#pragma unroll
  for (int e = 0; e < E_NUM; ++e) {
    float a0 = 0.f, a1 = 0.f, a2 = 0.f, a3 = 0.f;
#pragma unroll
    for (int j = 0; j < 4; ++j) {
      float4 wv = *(const float4*)(sgW + e * D_DIM + j * 256 + lane * 4);
      a0 += dot4(xv[0][j], wv);
      a1 += dot4(xv[1][j], wv);
      a2 += dot4(xv[2][j], wv);
      a3 += dot4(xv[3][j], wv);
    }
#pragma unroll
    for (int o = 32; o; o >>= 1) {
      a0 += __shfl_xor(a0, o);
      a1 += __shfl_xor(a1, o);
      a2 += __shfl_xor(a2, o);
      a3 += __shfl_xor(a3, o);
    }
    lg[0][e] = a0 + sgb[e];
    lg[1][e] = a1 + sgb[e];
    lg[2][e] = a2 + sgb[e];
    lg[3][e] = a3 + sgb[e];
  }

  // ---- top-2 per token (ties -> lower index, matches jax.lax.top_k) ----
  int e0[4], e1[4];
  float w0s[4], w1s[4];
#pragma unroll
  for (int tok = 0; tok < 4; ++tok) {
    int b0 = 0; float v0 = lg[tok][0];
#pragma unroll
    for (int e = 1; e < E_NUM; ++e) if (lg[tok][e] > v0) { v0 = lg[tok][e]; b0 = e; }
    int b1 = -1; float v1 = -3.0e38f;
#pragma unroll
    for (int e = 0; e < E_NUM; ++e) if (e != b0 && lg[tok][e] > v1) { v1 = lg[tok][e]; b1 = e; }
    const float pp = expf(v1 - v0);
    const float inv = 1.f / (1.f + pp);
    e0[tok] = b0; e1[tok] = b1;
    w0s[tok] = inv * 0.25f; w1s[tok] = pp * inv * 0.25f;  // fold softmax * SCALING
  }

  // ---- h for top-2 experts (bf16 LDS operands, R2 math), batched reduce ----
  float hv[4][8];
#pragma unroll
  for (int tok = 0; tok < 4; ++tok) {
#pragma unroll
    for (int q = 0; q < 8; ++q) {
      const int row = ((q < 4) ? e0[tok] : e1[tok]) * 4 + (q & 3);
      float s = 0.f;
#pragma unroll
      for (int j = 0; j < 4; ++j) {
        ushort4 uv = *(const ushort4*)(sld + row * D_DIM + j * 256 + lane * 4);
        s += xv[tok][j].x * bf2f(uv.x) + xv[tok][j].y * bf2f(uv.y) +
             xv[tok][j].z * bf2f(uv.z) + xv[tok][j].w * bf2f(uv.w);
      }
      hv[tok][q] = s;
    }
  }
#pragma unroll
  for (int o = 32; o; o >>= 1)
#pragma unroll
    for (int tok = 0; tok < 4; ++tok)
#pragma unroll
      for (int q = 0; q < 8; ++q)
        hv[tok][q] += __shfl_xor(hv[tok][q], o);

  if (lane == 0) {
#pragma unroll
    for (int tok = 0; tok < 4; ++tok) {
      const int t = tbase + tok;
      ids[t * 2] = e0[tok]; ids[t * 2 + 1] = e1[tok];
      const float s0 = w0s[tok], s1 = w1s[tok];
      *(float4*)(cvals + t * 8) =
          make_float4(hv[tok][0] * s0, hv[tok][1] * s0, hv[tok][2] * s0, hv[tok][3] * s0);
      *(float4*)(cvals + t * 8 + 4) =
          make_float4(hv[tok][4] * s1, hv[tok][5] * s1, hv[tok][6] * s1, hv[tok][7] * s1);
    }
  }
}

// ---------------- main GEMM (fp32 A, reg-staged) — R2-proven bit-for-bit ----
__global__ __launch_bounds__(256, 2)
void moe_gemm_f32(const float* __restrict__ x, const u16* __restrict__ Wb,
                  const float* __restrict__ bias, const int* __restrict__ ids,
                  const float* __restrict__ cvals, const float* __restrict__ lup,
                  float* __restrict__ out) {
  __shared__ u16 Al[128 * 64];
  __shared__ u16 Bl[128 * 64];
  const int tid = threadIdx.x, lane = tid & 63, wid = tid >> 6;
  const int wm = wid >> 1, wn = wid & 1;
  const int p = blockIdx.x;
  const int cx = p & 7, q = p >> 3;
  const int nb = q & 7, mb = cx * 16 + (q >> 3);
  const int m0 = mb * 128, n0 = nb * 128;
  f32x4 acc[4][4] = {};
  float4 av[8];
#pragma unroll
  for (int t = 0; t < 8; ++t) {
    int c = t * 256 + tid, row = c >> 4, k4 = c & 15;
    av[t] = *(const float4*)(x + (size_t)(m0 + row) * D_DIM + k4 * 4);
  }
#pragma unroll 1
  for (int kt = 0; kt < 16; ++kt) {
    const int k0 = kt * 64;
#pragma unroll
    for (int i = 0; i < 4; ++i) {
      int c = i * 256 + tid, row = c >> 3, kc = (c & 7) ^ (row & 7);
      __builtin_amdgcn_global_load_lds(
          (const __attribute__((address_space(1))) u32*)(Wb + (size_t)(n0 + row) * D_DIM + k0 + kc * 8),
          (__attribute__((address_space(3))) u32*)&Bl[c * 8], 16, 0, 0);
    }
#pragma unroll
    for (int t = 0; t < 8; ++t) {
      int c = t * 256 + tid, row = c >> 4, k4 = c & 15;
      int off = (row * 128 + k4 * 8) ^ ((row & 7) << 4);
      *(ushort4*)((char*)Al + off) =
          make_ushort4(f2bf(av[t].x), f2bf(av[t].y), f2bf(av[t].z), f2bf(av[t].w));
    }
    __syncthreads();
    if (kt < 15) {
#pragma unroll
      for (int t = 0; t < 8; ++t) {
        int c = t * 256 + tid, row = c >> 4, k4 = c & 15;
        av[t] = *(const float4*)(x + (size_t)(m0 + row) * D_DIM + (k0 + 64) + k4 * 4);
      }
    }
#pragma unroll
    for (int kk = 0; kk < 2; ++kk) {
      bf16x8 af[4], bfr[4];
      const int kb = kk * 64 + ((lane >> 4) * 16);
#pragma unroll
      for (int m = 0; m < 4; ++m) {
        int row = wm * 64 + m * 16 + (lane & 15);
        af[m] = *(const bf16x8*)((const char*)Al + ((row * 128 + kb) ^ ((row & 7) << 4)));
      }
#pragma unroll
      for (int n = 0; n < 4; ++n) {
        int row = wn * 64 + n * 16 + (lane & 15);
        bfr[n] = *(const bf16x8*)((const char*)Bl + ((row * 128 + kb) ^ ((row & 7) << 4)));
      }
#pragma unroll
      for (int m = 0; m < 4; ++m)
#pragma unroll
        for (int n = 0; n < 4; ++n)
          acc[m][n] = __builtin_amdgcn_mfma_f32_16x16x32_bf16(af[m], bfr[n], acc[m][n], 0, 0, 0);
    }
    __syncthreads();
  }
  const int rg = lane >> 4, cl = lane & 15;
  const int baser = m0 + wm * 64, basec = n0 + wn * 64;
  float bs[4];
#pragma unroll
  for (int n = 0; n < 4; ++n) bs[n] = bias[basec + n * 16 + cl];
#pragma unroll
  for (int m = 0; m < 4; ++m)
#pragma unroll
    for (int j = 0; j < 4; ++j) {
      const int rr = baser + m * 16 + rg * 4 + j;
      const int2 id2 = *(const int2*)(ids + rr * 2);
      const float4 c0 = *(const float4*)(cvals + rr * 8);
      const float4 c1 = *(const float4*)(cvals + rr * 8 + 4);
      const float* u0b = lup + (size_t)id2.x * (D_DIM * 4);
      const float* u1b = lup + (size_t)id2.y * (D_DIM * 4);
#pragma unroll
      for (int n = 0; n < 4; ++n) {
        const int cc = basec + n * 16 + cl;
        float4 u0 = *(const float4*)(u0b + cc * 4);
        float4 u1 = *(const float4*)(u1b + cc * 4);
        float v = acc[m][n][j] + bs[n];
        v += c0.x * u0.x + c0.y * u0.y + c0.z * u0.z + c0.w * u0.w;
        v += c1.x * u1.x + c1.y * u1.y + c1.z * u1.z + c1.w * u1.w;
        out[(size_t)rr * D_DIM + cc] = v;
      }
    }
}

extern "C" void kernel_launch(void* const* d_in, const int* in_sizes, int n_in,
                              void* d_out, int out_size, void* d_ws, size_t ws_size,
                              hipStream_t stream) {
  const float* x   = (const float*)d_in[0];
  const float* Wb_ = (const float*)d_in[1];
  const float* bb  = (const float*)d_in[2];
  const float* gW  = (const float*)d_in[3];
  const float* gb  = (const float*)d_in[4];
  const float* ld  = (const float*)d_in[5];
  const float* lup = (const float*)d_in[6];

  // ws layout (R2-proven): [0,2M) W bf16 | [2M,+128K) ids | [+,512K) cvals
  char* w = (char*)d_ws;
  u16*   Wbf   = (u16*)w;
  int*   ids   = (int*)(w + (2u << 20));
  float* cvals = (float*)(w + (2u << 20) + (128u << 10));

  hipLaunchKernelGGL(conv_w,    dim3(512),  dim3(256),  0, stream, Wb_, Wbf);
  hipLaunchKernelGGL(moe_prep2, dim3(256),  dim3(1024), 0, stream, x, gW, gb, ld, ids, cvals);
  hipLaunchKernelGGL(moe_gemm_f32, dim3(1024), dim3(256), 0, stream,
                     x, Wbf, bb, ids, cvals, lup, (float*)d_out);
}

// Round 7
// 130.677 us; speedup vs baseline: 2.1330x; 2.1330x over previous
//
#include <hip/hip_runtime.h>
#include <hip/hip_bf16.h>
#include <cstdint>
#include <cstddef>

// B=4, S=4096, D=1024, E=10, R=4, TOPK=2, SCALING=0.25
#define D_DIM 1024
#define E_NUM 10

typedef __attribute__((ext_vector_type(8))) short bf16x8;
typedef __attribute__((ext_vector_type(4))) float f32x4;
typedef unsigned short u16;
typedef unsigned int u32;

__device__ __forceinline__ u16 f2bf(float f) {
  union { float f; u32 u; } v; v.f = f;
  u32 r = v.u + 0x7fffu + ((v.u >> 16) & 1u);   // RNE
  return (u16)(r >> 16);
}
__device__ __forceinline__ float bf2f(u16 u) {
  union { u32 u; float f; } v; v.u = ((u32)u) << 16; return v.f;
}
__device__ __forceinline__ float dot4(float4 a, float4 b) {
  return a.x * b.x + a.y * b.y + a.z * b.z + a.w * b.w;
}

// ---------------- W_base fp32 -> bf16 (proven) ----------------
__global__ void conv_w(const float* __restrict__ W, u16* __restrict__ Wb) {
  const int i = (blockIdx.x * 256 + threadIdx.x) * 8;
  float4 a = *(const float4*)(W + i);
  float4 b = *(const float4*)(W + i + 4);
  *(ushort4*)(Wb + i)     = make_ushort4(f2bf(a.x), f2bf(a.y), f2bf(a.z), f2bf(a.w));
  *(ushort4*)(Wb + i + 4) = make_ushort4(f2bf(b.x), f2bf(b.y), f2bf(b.z), f2bf(b.w));
}

// ---------------- Bld[48][1024] bf16: rows 0-39 = lora_down, 40-47 = 0 ------
__global__ void prep_ldb(const float* __restrict__ ld, u16* __restrict__ Bld) {
  const int r = blockIdx.x;   // 48
  for (int c = threadIdx.x; c < D_DIM; c += 256)
    Bld[r * D_DIM + c] = (r < 40) ? f2bf(ld[r * D_DIM + c]) : (u16)0;
}

// ---------------- h via MFMA, 4-way k-split across waves --------------------
// grid 1024 x 256 thr; block = 16 tokens; wave w owns k-quarter [w*256,+256).
// Per-wave private LDS slabs; partial accs combined via LDS at the end.
__global__ __launch_bounds__(256)
void moe_prep_h(const float* __restrict__ x, const u16* __restrict__ Bld,
                float* __restrict__ h_all) {
  __shared__ u16 sX[4][16 * 64];        // 2 KB/wave, swizzled
  __shared__ u16 sB[4][48 * 64];        // 6 KB/wave, swizzled
  __shared__ float sP[4][3][16][17];    // ~12.75 KB partial accs

  const int tid = threadIdx.x, lane = tid & 63, w = tid >> 6;
  const int r0 = blockIdx.x * 16;
  const int kbase = w * 256;

  f32x4 acc[3] = {};

  float4 av[4];
#pragma unroll
  for (int i = 0; i < 2; ++i) {               // preload kt=0 (2 chunks/lane)
    const int c = lane * 2 + i, row = c >> 3, kc = c & 7;
    const float* g = x + (size_t)(r0 + row) * D_DIM + kbase + kc * 8;
    av[i * 2]     = *(const float4*)g;
    av[i * 2 + 1] = *(const float4*)(g + 4);
  }

#pragma unroll 1
  for (int kt = 0; kt < 4; ++kt) {
    const int k0 = kbase + kt * 64;
    // B slab: 384 16B-chunks; source-chunk XOR -> linear dest = swizzled
#pragma unroll
    for (int i = 0; i < 6; ++i) {
      const int c = i * 64 + lane, row = c >> 3, kc = (c & 7) ^ (row & 7);
      __builtin_amdgcn_global_load_lds(
          (const __attribute__((address_space(1))) u32*)(Bld + (size_t)row * D_DIM + k0 + kc * 8),
          (__attribute__((address_space(3))) u32*)&sB[w][c * 8], 16, 0, 0);
    }
    // X slab: convert fp32->bf16, swizzled 16B writes
#pragma unroll
    for (int i = 0; i < 2; ++i) {
      const int c = lane * 2 + i, row = c >> 3, kc = c & 7;
      const float4 a = av[i * 2], b = av[i * 2 + 1];
      const int off = (row * 128 + kc * 16) ^ ((row & 7) << 4);
      *(ushort4*)((char*)sX[w] + off)     = make_ushort4(f2bf(a.x), f2bf(a.y), f2bf(a.z), f2bf(a.w));
      *(ushort4*)((char*)sX[w] + off + 8) = make_ushort4(f2bf(b.x), f2bf(b.y), f2bf(b.z), f2bf(b.w));
    }
    __syncthreads();
    if (kt < 3) {
#pragma unroll
      for (int i = 0; i < 2; ++i) {           // prefetch next k-tile
        const int c = lane * 2 + i, row = c >> 3, kc = c & 7;
        const float* g = x + (size_t)(r0 + row) * D_DIM + (k0 + 64) + kc * 8;
        av[i * 2]     = *(const float4*)g;
        av[i * 2 + 1] = *(const float4*)(g + 4);
      }
    }
#pragma unroll
    for (int kk = 0; kk < 2; ++kk) {
      const int kb = kk * 64 + ((lane >> 4) * 16);
      const int rA = lane & 15;
      const bf16x8 a0 = *(const bf16x8*)((const char*)sX[w] + ((rA * 128 + kb) ^ ((rA & 7) << 4)));
#pragma unroll
      for (int cf = 0; cf < 3; ++cf) {
        const int rB = cf * 16 + (lane & 15);
        const bf16x8 q = *(const bf16x8*)((const char*)sB[w] + ((rB * 128 + kb) ^ ((rB & 7) << 4)));
        acc[cf] = __builtin_amdgcn_mfma_f32_16x16x32_bf16(a0, q, acc[cf], 0, 0, 0);
      }
    }
    __syncthreads();
  }

  // combine 4 k-partials -> h_all
#pragma unroll
  for (int cf = 0; cf < 3; ++cf)
#pragma unroll
    for (int j = 0; j < 4; ++j)
      sP[w][cf][(lane >> 4) * 4 + j][lane & 15] = acc[cf][j];
  __syncthreads();

  const int row = tid >> 4, c16 = tid & 15;
#pragma unroll
  for (int cf = 0; cf < 3; ++cf) {
    const int col = cf * 16 + c16;
    if (col < 40) {
      const float s = sP[0][cf][row][c16] + sP[1][cf][row][c16] +
                      sP[2][cf][row][c16] + sP[3][cf][row][c16];
      h_all[(size_t)(r0 + row) * 40 + col] = s;
    }
  }
}

// ---------------- gating (exact R6 fp32 math) + coeff assembly --------------
// grid 1024 x 256 thr; block = 16 tokens; wave w = 4 tokens, reg-ILP, no spill.
__global__ __launch_bounds__(256, 2)
void moe_gate(const float* __restrict__ x, const float* __restrict__ gW,
              const float* __restrict__ gb, const float* __restrict__ h_all,
              int* __restrict__ ids, float* __restrict__ cvals) {
  __shared__ float sgW[E_NUM * D_DIM];   // 40 KB
  __shared__ float sgb[16];
  const int tid = threadIdx.x, lane = tid & 63, w = tid >> 6;
  for (int i = tid; i < E_NUM * D_DIM; i += 256) sgW[i] = gW[i];
  if (tid < E_NUM) sgb[tid] = gb[tid];
  __syncthreads();

  const int tb = blockIdx.x * 16 + w * 4;

  float4 xv[4][4];
#pragma unroll
  for (int tok = 0; tok < 4; ++tok)
#pragma unroll
    for (int j = 0; j < 4; ++j)
      xv[tok][j] = *(const float4*)(x + (size_t)(tb + tok) * D_DIM + j * 256 + lane * 4);

  float lg[4][E_NUM];
#pragma unroll
  for (int e = 0; e < E_NUM; ++e) {
    float a0 = 0.f, a1 = 0.f, a2 = 0.f, a3 = 0.f;
#pragma unroll
    for (int j = 0; j < 4; ++j) {
      const float4 wv = *(const float4*)(sgW + e * D_DIM + j * 256 + lane * 4);
      a0 += dot4(xv[0][j], wv);
      a1 += dot4(xv[1][j], wv);
      a2 += dot4(xv[2][j], wv);
      a3 += dot4(xv[3][j], wv);
    }
#pragma unroll
    for (int o = 32; o; o >>= 1) {
      a0 += __shfl_xor(a0, o);
      a1 += __shfl_xor(a1, o);
      a2 += __shfl_xor(a2, o);
      a3 += __shfl_xor(a3, o);
    }
    lg[0][e] = a0 + sgb[e];
    lg[1][e] = a1 + sgb[e];
    lg[2][e] = a2 + sgb[e];
    lg[3][e] = a3 + sgb[e];
  }

  if (lane < 4) {
    const int tok = lane, t = tb + tok;
    int e0 = 0; float v0 = lg[tok][0];
#pragma unroll
    for (int e = 1; e < E_NUM; ++e) if (lg[tok][e] > v0) { v0 = lg[tok][e]; e0 = e; }
    int e1 = -1; float v1 = -3.0e38f;
#pragma unroll
    for (int e = 0; e < E_NUM; ++e) if (e != e0 && lg[tok][e] > v1) { v1 = lg[tok][e]; e1 = e; }
    const float pp = expf(v1 - v0);
    const float inv = 1.f / (1.f + pp);
    const float s0 = inv * 0.25f, s1 = pp * inv * 0.25f;   // softmax * SCALING
    ids[t * 2] = e0; ids[t * 2 + 1] = e1;
    const float4 h0 = *(const float4*)(h_all + (size_t)t * 40 + e0 * 4);
    const float4 h1 = *(const float4*)(h_all + (size_t)t * 40 + e1 * 4);
    *(float4*)(cvals + t * 8)     = make_float4(h0.x * s0, h0.y * s0, h0.z * s0, h0.w * s0);
    *(float4*)(cvals + t * 8 + 4) = make_float4(h1.x * s1, h1.y * s1, h1.z * s1, h1.w * s1);
  }
}

// ---------------- main GEMM (fp32 A, reg-staged) — R2/R6-proven -------------
__global__ __launch_bounds__(256, 2)
void moe_gemm_f32(const float* __restrict__ x, const u16* __restrict__ Wb,
                  const float* __restrict__ bias, const int* __restrict__ ids,
                  const float* __restrict__ cvals, const float* __restrict__ lup,
                  float* __restrict__ out) {
  __shared__ u16 Al[128 * 64];
  __shared__ u16 Bl[128 * 64];
  const int tid = threadIdx.x, lane = tid & 63, wid = tid >> 6;
  const int wm = wid >> 1, wn = wid & 1;
  const int p = blockIdx.x;
  const int cx = p & 7, q = p >> 3;
  const int nb = q & 7, mb = cx * 16 + (q >> 3);
  const int m0 = mb * 128, n0 = nb * 128;
  f32x4 acc[4][4] = {};
  float4 av[8];
#pragma unroll
  for (int t = 0; t < 8; ++t) {
    int c = t * 256 + tid, row = c >> 4, k4 = c & 15;
    av[t] = *(const float4*)(x + (size_t)(m0 + row) * D_DIM + k4 * 4);
  }
#pragma unroll 1
  for (int kt = 0; kt < 16; ++kt) {
    const int k0 = kt * 64;
#pragma unroll
    for (int i = 0; i < 4; ++i) {
      int c = i * 256 + tid, row = c >> 3, kc = (c & 7) ^ (row & 7);
      __builtin_amdgcn_global_load_lds(
          (const __attribute__((address_space(1))) u32*)(Wb + (size_t)(n0 + row) * D_DIM + k0 + kc * 8),
          (__attribute__((address_space(3))) u32*)&Bl[c * 8], 16, 0, 0);
    }
#pragma unroll
    for (int t = 0; t < 8; ++t) {
      int c = t * 256 + tid, row = c >> 4, k4 = c & 15;
      int off = (row * 128 + k4 * 8) ^ ((row & 7) << 4);
      *(ushort4*)((char*)Al + off) =
          make_ushort4(f2bf(av[t].x), f2bf(av[t].y), f2bf(av[t].z), f2bf(av[t].w));
    }
    __syncthreads();
    if (kt < 15) {
#pragma unroll
      for (int t = 0; t < 8; ++t) {
        int c = t * 256 + tid, row = c >> 4, k4 = c & 15;
        av[t] = *(const float4*)(x + (size_t)(m0 + row) * D_DIM + (k0 + 64) + k4 * 4);
      }
    }
#pragma unroll
    for (int kk = 0; kk < 2; ++kk) {
      bf16x8 af[4], bfr[4];
      const int kb = kk * 64 + ((lane >> 4) * 16);
#pragma unroll
      for (int m = 0; m < 4; ++m) {
        int row = wm * 64 + m * 16 + (lane & 15);
        af[m] = *(const bf16x8*)((const char*)Al + ((row * 128 + kb) ^ ((row & 7) << 4)));
      }
#pragma unroll
      for (int n = 0; n < 4; ++n) {
        int row = wn * 64 + n * 16 + (lane & 15);
        bfr[n] = *(const bf16x8*)((const char*)Bl + ((row * 128 + kb) ^ ((row & 7) << 4)));
      }
#pragma unroll
      for (int m = 0; m < 4; ++m)
#pragma unroll
        for (int n = 0; n < 4; ++n)
          acc[m][n] = __builtin_amdgcn_mfma_f32_16x16x32_bf16(af[m], bfr[n], acc[m][n], 0, 0, 0);
    }
    __syncthreads();
  }
  const int rg = lane >> 4, cl = lane & 15;
  const int baser = m0 + wm * 64, basec = n0 + wn * 64;
  float bs[4];
#pragma unroll
  for (int n = 0; n < 4; ++n) bs[n] = bias[basec + n * 16 + cl];
#pragma unroll
  for (int m = 0; m < 4; ++m)
#pragma unroll
    for (int j = 0; j < 4; ++j) {
      const int rr = baser + m * 16 + rg * 4 + j;
      const int2 id2 = *(const int2*)(ids + rr * 2);
      const float4 c0 = *(const float4*)(cvals + rr * 8);
      const float4 c1 = *(const float4*)(cvals + rr * 8 + 4);
      const float* u0b = lup + (size_t)id2.x * (D_DIM * 4);
      const float* u1b = lup + (size_t)id2.y * (D_DIM * 4);
#pragma unroll
      for (int n = 0; n < 4; ++n) {
        const int cc = basec + n * 16 + cl;
        float4 u0 = *(const float4*)(u0b + cc * 4);
        float4 u1 = *(const float4*)(u1b + cc * 4);
        float v = acc[m][n][j] + bs[n];
        v += c0.x * u0.x + c0.y * u0.y + c0.z * u0.z + c0.w * u0.w;
        v += c1.x * u1.x + c1.y * u1.y + c1.z * u1.z + c1.w * u1.w;
        out[(size_t)rr * D_DIM + cc] = v;
      }
    }
}

extern "C" void kernel_launch(void* const* d_in, const int* in_sizes, int n_in,
                              void* d_out, int out_size, void* d_ws, size_t ws_size,
                              hipStream_t stream) {
  const float* x   = (const float*)d_in[0];
  const float* Wb_ = (const float*)d_in[1];
  const float* bb  = (const float*)d_in[2];
  const float* gW  = (const float*)d_in[3];
  const float* gb  = (const float*)d_in[4];
  const float* ld  = (const float*)d_in[5];
  const float* lup = (const float*)d_in[6];

  // ws (KB): Wbf 0-2048 | Bld 2048-2144 | ids 2144-2272 | cvals 2272-2784 |
  //          h_all 2784-5344   (total ~5.3 MB)
  char* w = (char*)d_ws;
  u16*   Wbf   = (u16*)w;
  u16*   Bld   = (u16*)(w + 2048ull * 1024);
  int*   ids   = (int*)(w + 2144ull * 1024);
  float* cvals = (float*)(w + 2272ull * 1024);
  float* h_all = (float*)(w + 2784ull * 1024);

  hipLaunchKernelGGL(conv_w,     dim3(512),  dim3(256), 0, stream, Wb_, Wbf);
  hipLaunchKernelGGL(prep_ldb,   dim3(48),   dim3(256), 0, stream, ld, Bld);
  hipLaunchKernelGGL(moe_prep_h, dim3(1024), dim3(256), 0, stream, x, Bld, h_all);
  hipLaunchKernelGGL(moe_gate,   dim3(1024), dim3(256), 0, stream, x, gW, gb, h_all, ids, cvals);
  hipLaunchKernelGGL(moe_gemm_f32, dim3(1024), dim3(256), 0, stream,
                     x, Wbf, bb, ids, cvals, lup, (float*)d_out);
}

// Round 8
// 118.167 us; speedup vs baseline: 2.3588x; 1.1059x over previous
//
#include <hip/hip_runtime.h>
#include <hip/hip_bf16.h>
#include <cstdint>
#include <cstddef>

// B=4, S=4096, D=1024, E=10, R=4, TOPK=2, SCALING=0.25
#define D_DIM 1024
#define E_NUM 10

typedef __attribute__((ext_vector_type(8))) short bf16x8;
typedef __attribute__((ext_vector_type(4))) float f32x4;
typedef unsigned short u16;
typedef unsigned int u32;

__device__ __forceinline__ u16 f2bf(float f) {
  union { float f; u32 u; } v; v.f = f;
  u32 r = v.u + 0x7fffu + ((v.u >> 16) & 1u);   // RNE
  return (u16)(r >> 16);
}
__device__ __forceinline__ float bf2f(u16 u) {
  union { u32 u; float f; } v; v.u = ((u32)u) << 16; return v.f;
}
__device__ __forceinline__ float dot4(float4 a, float4 b) {
  return a.x * b.x + a.y * b.y + a.z * b.z + a.w * b.w;
}

// ---------------- W_base fp32 -> bf16 (proven) ----------------
__global__ void conv_w(const float* __restrict__ W, u16* __restrict__ Wb) {
  const int i = (blockIdx.x * 256 + threadIdx.x) * 8;
  float4 a = *(const float4*)(W + i);
  float4 b = *(const float4*)(W + i + 4);
  *(ushort4*)(Wb + i)     = make_ushort4(f2bf(a.x), f2bf(a.y), f2bf(a.z), f2bf(a.w));
  *(ushort4*)(Wb + i + 4) = make_ushort4(f2bf(b.x), f2bf(b.y), f2bf(b.z), f2bf(b.w));
}

// ---------------- Bld[48][1024] bf16: rows 0-39 = lora_down, 40-47 = 0 ------
__global__ void prep_ldb(const float* __restrict__ ld, u16* __restrict__ Bld) {
  const int r = blockIdx.x;   // 48
  for (int c = threadIdx.x; c < D_DIM; c += 256)
    Bld[r * D_DIM + c] = (r < 40) ? f2bf(ld[r * D_DIM + c]) : (u16)0;
}

// ---------------- h via MFMA, 4-way k-split across waves (R7-proven) --------
// grid 1024 x 256 thr; block = 16 tokens; wave w owns k-quarter [w*256,+256).
// NEW vs R7: also emits xb = f2bf(x) for the main GEMM's A operand.
__global__ __launch_bounds__(256)
void moe_prep_h(const float* __restrict__ x, const u16* __restrict__ Bld,
                float* __restrict__ h_all, u16* __restrict__ xb) {
  __shared__ u16 sX[4][16 * 64];        // 2 KB/wave, swizzled
  __shared__ u16 sB[4][48 * 64];        // 6 KB/wave, swizzled
  __shared__ float sP[4][3][16][17];    // ~12.75 KB partial accs

  const int tid = threadIdx.x, lane = tid & 63, w = tid >> 6;
  const int r0 = blockIdx.x * 16;
  const int kbase = w * 256;

  f32x4 acc[3] = {};

  float4 av[4];
#pragma unroll
  for (int i = 0; i < 2; ++i) {               // preload kt=0 (2 chunks/lane)
    const int c = lane * 2 + i, row = c >> 3, kc = c & 7;
    const float* g = x + (size_t)(r0 + row) * D_DIM + kbase + kc * 8;
    av[i * 2]     = *(const float4*)g;
    av[i * 2 + 1] = *(const float4*)(g + 4);
  }

#pragma unroll 1
  for (int kt = 0; kt < 4; ++kt) {
    const int k0 = kbase + kt * 64;
    // B slab: 384 16B-chunks; source-chunk XOR -> linear dest = swizzled
#pragma unroll
    for (int i = 0; i < 6; ++i) {
      const int c = i * 64 + lane, row = c >> 3, kc = (c & 7) ^ (row & 7);
      __builtin_amdgcn_global_load_lds(
          (const __attribute__((address_space(1))) u32*)(Bld + (size_t)row * D_DIM + k0 + kc * 8),
          (__attribute__((address_space(3))) u32*)&sB[w][c * 8], 16, 0, 0);
    }
    // X slab: convert fp32->bf16, swizzled 16B writes; also write xb (linear)
#pragma unroll
    for (int i = 0; i < 2; ++i) {
      const int c = lane * 2 + i, row = c >> 3, kc = c & 7;
      const float4 a = av[i * 2], b = av[i * 2 + 1];
      const ushort4 ha = make_ushort4(f2bf(a.x), f2bf(a.y), f2bf(a.z), f2bf(a.w));
      const ushort4 hb = make_ushort4(f2bf(b.x), f2bf(b.y), f2bf(b.z), f2bf(b.w));
      const int off = (row * 128 + kc * 16) ^ ((row & 7) << 4);
      *(ushort4*)((char*)sX[w] + off)     = ha;
      *(ushort4*)((char*)sX[w] + off + 8) = hb;
      if (xb) {
        u16* dst = xb + (size_t)(r0 + row) * D_DIM + k0 + kc * 8;
        *(ushort4*)dst       = ha;
        *(ushort4*)(dst + 4) = hb;
      }
    }
    __syncthreads();
    if (kt < 3) {
#pragma unroll
      for (int i = 0; i < 2; ++i) {           // prefetch next k-tile
        const int c = lane * 2 + i, row = c >> 3, kc = c & 7;
        const float* g = x + (size_t)(r0 + row) * D_DIM + (k0 + 64) + kc * 8;
        av[i * 2]     = *(const float4*)g;
        av[i * 2 + 1] = *(const float4*)(g + 4);
      }
    }
#pragma unroll
    for (int kk = 0; kk < 2; ++kk) {
      const int kb = kk * 64 + ((lane >> 4) * 16);
      const int rA = lane & 15;
      const bf16x8 a0 = *(const bf16x8*)((const char*)sX[w] + ((rA * 128 + kb) ^ ((rA & 7) << 4)));
#pragma unroll
      for (int cf = 0; cf < 3; ++cf) {
        const int rB = cf * 16 + (lane & 15);
        const bf16x8 q = *(const bf16x8*)((const char*)sB[w] + ((rB * 128 + kb) ^ ((rB & 7) << 4)));
        acc[cf] = __builtin_amdgcn_mfma_f32_16x16x32_bf16(a0, q, acc[cf], 0, 0, 0);
      }
    }
    __syncthreads();
  }

  // combine 4 k-partials -> h_all
#pragma unroll
  for (int cf = 0; cf < 3; ++cf)
#pragma unroll
    for (int j = 0; j < 4; ++j)
      sP[w][cf][(lane >> 4) * 4 + j][lane & 15] = acc[cf][j];
  __syncthreads();

  const int row = tid >> 4, c16 = tid & 15;
#pragma unroll
  for (int cf = 0; cf < 3; ++cf) {
    const int col = cf * 16 + c16;
    if (col < 40) {
      const float s = sP[0][cf][row][c16] + sP[1][cf][row][c16] +
                      sP[2][cf][row][c16] + sP[3][cf][row][c16];
      h_all[(size_t)(r0 + row) * 40 + col] = s;
    }
  }
}

// ---------------- gating (R7-proven fp32 math) + coeff assembly -------------
__global__ __launch_bounds__(256, 2)
void moe_gate(const float* __restrict__ x, const float* __restrict__ gW,
              const float* __restrict__ gb, const float* __restrict__ h_all,
              int* __restrict__ ids, float* __restrict__ cvals) {
  __shared__ float sgW[E_NUM * D_DIM];   // 40 KB
  __shared__ float sgb[16];
  const int tid = threadIdx.x, lane = tid & 63, w = tid >> 6;
  for (int i = tid; i < E_NUM * D_DIM; i += 256) sgW[i] = gW[i];
  if (tid < E_NUM) sgb[tid] = gb[tid];
  __syncthreads();

  const int tb = blockIdx.x * 16 + w * 4;

  float4 xv[4][4];
#pragma unroll
  for (int tok = 0; tok < 4; ++tok)
#pragma unroll
    for (int j = 0; j < 4; ++j)
      xv[tok][j] = *(const float4*)(x + (size_t)(tb + tok) * D_DIM + j * 256 + lane * 4);

  float lg[4][E_NUM];
#pragma unroll
  for (int e = 0; e < E_NUM; ++e) {
    float a0 = 0.f, a1 = 0.f, a2 = 0.f, a3 = 0.f;
#pragma unroll
    for (int j = 0; j < 4; ++j) {
      const float4 wv = *(const float4*)(sgW + e * D_DIM + j * 256 + lane * 4);
      a0 += dot4(xv[0][j], wv);
      a1 += dot4(xv[1][j], wv);
      a2 += dot4(xv[2][j], wv);
      a3 += dot4(xv[3][j], wv);
    }
#pragma unroll
    for (int o = 32; o; o >>= 1) {
      a0 += __shfl_xor(a0, o);
      a1 += __shfl_xor(a1, o);
      a2 += __shfl_xor(a2, o);
      a3 += __shfl_xor(a3, o);
    }
    lg[0][e] = a0 + sgb[e];
    lg[1][e] = a1 + sgb[e];
    lg[2][e] = a2 + sgb[e];
    lg[3][e] = a3 + sgb[e];
  }

  if (lane < 4) {
    const int tok = lane, t = tb + tok;
    int e0 = 0; float v0 = lg[tok][0];
#pragma unroll
    for (int e = 1; e < E_NUM; ++e) if (lg[tok][e] > v0) { v0 = lg[tok][e]; e0 = e; }
    int e1 = -1; float v1 = -3.0e38f;
#pragma unroll
    for (int e = 0; e < E_NUM; ++e) if (e != e0 && lg[tok][e] > v1) { v1 = lg[tok][e]; e1 = e; }
    const float pp = expf(v1 - v0);
    const float inv = 1.f / (1.f + pp);
    const float s0 = inv * 0.25f, s1 = pp * inv * 0.25f;   // softmax * SCALING
    ids[t * 2] = e0; ids[t * 2 + 1] = e1;
    const float4 h0 = *(const float4*)(h_all + (size_t)t * 40 + e0 * 4);
    const float4 h1 = *(const float4*)(h_all + (size_t)t * 40 + e1 * 4);
    *(float4*)(cvals + t * 8)     = make_float4(h0.x * s0, h0.y * s0, h0.z * s0, h0.w * s0);
    *(float4*)(cvals + t * 8 + 4) = make_float4(h1.x * s1, h1.y * s1, h1.z * s1, h1.w * s1);
  }
}

// ---------------- main GEMM: bf16 A from xb, A+B via global_load_lds --------
__global__ __launch_bounds__(256, 2)
void moe_gemm_bf(const u16* __restrict__ xb, const u16* __restrict__ Wb,
                 const float* __restrict__ bias, const int* __restrict__ ids,
                 const float* __restrict__ cvals, const float* __restrict__ lup,
                 float* __restrict__ out) {
  __shared__ u16 Al[128 * 64];
  __shared__ u16 Bl[128 * 64];

  const int tid = threadIdx.x, lane = tid & 63, wid = tid >> 6;
  const int wm = wid >> 1, wn = wid & 1;
  const int p = blockIdx.x;
  const int cx = p & 7, q = p >> 3;
  const int nb = q & 7, mb = cx * 16 + (q >> 3);
  const int m0 = mb * 128, n0 = nb * 128;

  f32x4 acc[4][4] = {};

#pragma unroll 1
  for (int kt = 0; kt < 16; ++kt) {
    const int k0 = kt * 64;
#pragma unroll
    for (int i = 0; i < 4; ++i) {                     // A tile
      int c = i * 256 + tid, row = c >> 3, kc = (c & 7) ^ (row & 7);
      __builtin_amdgcn_global_load_lds(
          (const __attribute__((address_space(1))) u32*)(xb + (size_t)(m0 + row) * D_DIM + k0 + kc * 8),
          (__attribute__((address_space(3))) u32*)&Al[c * 8], 16, 0, 0);
    }
#pragma unroll
    for (int i = 0; i < 4; ++i) {                     // B tile
      int c = i * 256 + tid, row = c >> 3, kc = (c & 7) ^ (row & 7);
      __builtin_amdgcn_global_load_lds(
          (const __attribute__((address_space(1))) u32*)(Wb + (size_t)(n0 + row) * D_DIM + k0 + kc * 8),
          (__attribute__((address_space(3))) u32*)&Bl[c * 8], 16, 0, 0);
    }
    __syncthreads();
#pragma unroll
    for (int kk = 0; kk < 2; ++kk) {
      bf16x8 af[4], bfr[4];
      const int kb = kk * 64 + ((lane >> 4) * 16);
#pragma unroll
      for (int m = 0; m < 4; ++m) {
        int row = wm * 64 + m * 16 + (lane & 15);
        af[m] = *(const bf16x8*)((const char*)Al + ((row * 128 + kb) ^ ((row & 7) << 4)));
      }
#pragma unroll
      for (int n = 0; n < 4; ++n) {
        int row = wn * 64 + n * 16 + (lane & 15);
        bfr[n] = *(const bf16x8*)((const char*)Bl + ((row * 128 + kb) ^ ((row & 7) << 4)));
      }
#pragma unroll
      for (int m = 0; m < 4; ++m)
#pragma unroll
        for (int n = 0; n < 4; ++n)
          acc[m][n] = __builtin_amdgcn_mfma_f32_16x16x32_bf16(af[m], bfr[n], acc[m][n], 0, 0, 0);
    }
    __syncthreads();
  }

  const int rg = lane >> 4, cl = lane & 15;
  const int baser = m0 + wm * 64, basec = n0 + wn * 64;
  float bs[4];
#pragma unroll
  for (int n = 0; n < 4; ++n) bs[n] = bias[basec + n * 16 + cl];
#pragma unroll
  for (int m = 0; m < 4; ++m)
#pragma unroll
    for (int j = 0; j < 4; ++j) {
      const int rr = baser + m * 16 + rg * 4 + j;
      const int2 id2 = *(const int2*)(ids + rr * 2);
      const float4 c0 = *(const float4*)(cvals + rr * 8);
      const float4 c1 = *(const float4*)(cvals + rr * 8 + 4);
      const float* u0b = lup + (size_t)id2.x * (D_DIM * 4);
      const float* u1b = lup + (size_t)id2.y * (D_DIM * 4);
#pragma unroll
      for (int n = 0; n < 4; ++n) {
        const int cc = basec + n * 16 + cl;
        float4 u0 = *(const float4*)(u0b + cc * 4);
        float4 u1 = *(const float4*)(u1b + cc * 4);
        float v = acc[m][n][j] + bs[n];
        v += c0.x * u0.x + c0.y * u0.y + c0.z * u0.z + c0.w * u0.w;
        v += c1.x * u1.x + c1.y * u1.y + c1.z * u1.z + c1.w * u1.w;
        out[(size_t)rr * D_DIM + cc] = v;
      }
    }
}

// ---------------- fallback GEMM (fp32 A, reg-staged) — R7-proven ------------
__global__ __launch_bounds__(256, 2)
void moe_gemm_f32(const float* __restrict__ x, const u16* __restrict__ Wb,
                  const float* __restrict__ bias, const int* __restrict__ ids,
                  const float* __restrict__ cvals, const float* __restrict__ lup,
                  float* __restrict__ out) {
  __shared__ u16 Al[128 * 64];
  __shared__ u16 Bl[128 * 64];
  const int tid = threadIdx.x, lane = tid & 63, wid = tid >> 6;
  const int wm = wid >> 1, wn = wid & 1;
  const int p = blockIdx.x;
  const int cx = p & 7, q = p >> 3;
  const int nb = q & 7, mb = cx * 16 + (q >> 3);
  const int m0 = mb * 128, n0 = nb * 128;
  f32x4 acc[4][4] = {};
  float4 av[8];
#pragma unroll
  for (int t = 0; t < 8; ++t) {
    int c = t * 256 + tid, row = c >> 4, k4 = c & 15;
    av[t] = *(const float4*)(x + (size_t)(m0 + row) * D_DIM + k4 * 4);
  }
#pragma unroll 1
  for (int kt = 0; kt < 16; ++kt) {
    const int k0 = kt * 64;
#pragma unroll
    for (int i = 0; i < 4; ++i) {
      int c = i * 256 + tid, row = c >> 3, kc = (c & 7) ^ (row & 7);
      __builtin_amdgcn_global_load_lds(
          (const __attribute__((address_space(1))) u32*)(Wb + (size_t)(n0 + row) * D_DIM + k0 + kc * 8),
          (__attribute__((address_space(3))) u32*)&Bl[c * 8], 16, 0, 0);
    }
#pragma unroll
    for (int t = 0; t < 8; ++t) {
      int c = t * 256 + tid, row = c >> 4, k4 = c & 15;
      int off = (row * 128 + k4 * 8) ^ ((row & 7) << 4);
      *(ushort4*)((char*)Al + off) =
          make_ushort4(f2bf(av[t].x), f2bf(av[t].y), f2bf(av[t].z), f2bf(av[t].w));
    }
    __syncthreads();
    if (kt < 15) {
#pragma unroll
      for (int t = 0; t < 8; ++t) {
        int c = t * 256 + tid, row = c >> 4, k4 = c & 15;
        av[t] = *(const float4*)(x + (size_t)(m0 + row) * D_DIM + (k0 + 64) + k4 * 4);
      }
    }
#pragma unroll
    for (int kk = 0; kk < 2; ++kk) {
      bf16x8 af[4], bfr[4];
      const int kb = kk * 64 + ((lane >> 4) * 16);
#pragma unroll
      for (int m = 0; m < 4; ++m) {
        int row = wm * 64 + m * 16 + (lane & 15);
        af[m] = *(const bf16x8*)((const char*)Al + ((row * 128 + kb) ^ ((row & 7) << 4)));
      }
#pragma unroll
      for (int n = 0; n < 4; ++n) {
        int row = wn * 64 + n * 16 + (lane & 15);
        bfr[n] = *(const bf16x8*)((const char*)Bl + ((row * 128 + kb) ^ ((row & 7) << 4)));
      }
#pragma unroll
      for (int m = 0; m < 4; ++m)
#pragma unroll
        for (int n = 0; n < 4; ++n)
          acc[m][n] = __builtin_amdgcn_mfma_f32_16x16x32_bf16(af[m], bfr[n], acc[m][n], 0, 0, 0);
    }
    __syncthreads();
  }
  const int rg = lane >> 4, cl = lane & 15;
  const int baser = m0 + wm * 64, basec = n0 + wn * 64;
  float bs[4];
#pragma unroll
  for (int n = 0; n < 4; ++n) bs[n] = bias[basec + n * 16 + cl];
#pragma unroll
  for (int m = 0; m < 4; ++m)
#pragma unroll
    for (int j = 0; j < 4; ++j) {
      const int rr = baser + m * 16 + rg * 4 + j;
      const int2 id2 = *(const int2*)(ids + rr * 2);
      const float4 c0 = *(const float4*)(cvals + rr * 8);
      const float4 c1 = *(const float4*)(cvals + rr * 8 + 4);
      const float* u0b = lup + (size_t)id2.x * (D_DIM * 4);
      const float* u1b = lup + (size_t)id2.y * (D_DIM * 4);
#pragma unroll
      for (int n = 0; n < 4; ++n) {
        const int cc = basec + n * 16 + cl;
        float4 u0 = *(const float4*)(u0b + cc * 4);
        float4 u1 = *(const float4*)(u1b + cc * 4);
        float v = acc[m][n][j] + bs[n];
        v += c0.x * u0.x + c0.y * u0.y + c0.z * u0.z + c0.w * u0.w;
        v += c1.x * u1.x + c1.y * u1.y + c1.z * u1.z + c1.w * u1.w;
        out[(size_t)rr * D_DIM + cc] = v;
      }
    }
}

extern "C" void kernel_launch(void* const* d_in, const int* in_sizes, int n_in,
                              void* d_out, int out_size, void* d_ws, size_t ws_size,
                              hipStream_t stream) {
  const float* x   = (const float*)d_in[0];
  const float* Wb_ = (const float*)d_in[1];
  const float* bb  = (const float*)d_in[2];
  const float* gW  = (const float*)d_in[3];
  const float* gb  = (const float*)d_in[4];
  const float* ld  = (const float*)d_in[5];
  const float* lup = (const float*)d_in[6];

  // ws (KB): Wbf 0-2048 | Bld 2048-2144 | ids 2144-2272 | cvals 2272-2784 |
  //          h_all 2784-5344 | xb 5632-38400  (~37.5 MB total)
  char* w = (char*)d_ws;
  u16*   Wbf   = (u16*)w;
  u16*   Bld   = (u16*)(w + 2048ull * 1024);
  int*   ids   = (int*)(w + 2144ull * 1024);
  float* cvals = (float*)(w + 2272ull * 1024);
  float* h_all = (float*)(w + 2784ull * 1024);
  const size_t need_full = (5632ull + 32768ull) * 1024;
  const bool full = ws_size >= need_full;
  u16* xb = full ? (u16*)(w + 5632ull * 1024) : nullptr;

  hipLaunchKernelGGL(conv_w,     dim3(512),  dim3(256), 0, stream, Wb_, Wbf);
  hipLaunchKernelGGL(prep_ldb,   dim3(48),   dim3(256), 0, stream, ld, Bld);
  hipLaunchKernelGGL(moe_prep_h, dim3(1024), dim3(256), 0, stream, x, Bld, h_all, xb);
  hipLaunchKernelGGL(moe_gate,   dim3(1024), dim3(256), 0, stream, x, gW, gb, h_all, ids, cvals);
  if (full)
    hipLaunchKernelGGL(moe_gemm_bf, dim3(1024), dim3(256), 0, stream,
                       xb, Wbf, bb, ids, cvals, lup, (float*)d_out);
  else
    hipLaunchKernelGGL(moe_gemm_f32, dim3(1024), dim3(256), 0, stream,
                       x, Wbf, bb, ids, cvals, lup, (float*)d_out);
}